// Round 1
// baseline (104.399 us; speedup 1.0000x reference)
//
#include <hip/hip_runtime.h>
#include <math.h>

// BoundaryDistanceLoss — H=W=1024 binary masks (float 0/1).
// edges = seg - erode3x3(seg); exact EDT of edges; loss =
// sigmoid((mean(target_edges*pred_dt) + mean(pred_edges*target_dt))/2).
//
// R15->R16: fuse finalization into k_main (last-block pattern). R15 profile:
// top-5 dispatches are all 41us ws-poison fills (268MB @ 80% HBM) -> k_main
// < 41us, and the residual controllable cost is the trailing 1-block k_fin
// (full drain + launch gap + L2 inv ~= 7us). Now: 4B memsetAsync zeroes a
// counter; each block release-adds it agent-scope; the single last block
// reduces the 2048 partials via agent-scope atomic loads (private-XCD L2 may
// hold stale poison lines for partial[] — plain loads unsafe, G16) and writes
// sigmoid. Also: phase-1's 5 cold float4 loads hoisted into registers before
// the shfl-combine pass (were serialized load->shfl rounds). Math identical
// to R13-R15 (absmax 0.0). Deterministic: exactly one finalizer block.
//
// ws layout: partial (8KB f32) + counter (4B u32 at offset 8192).

#define HW 1024
#define WIN 8
#define RPB 64
#define KROWS (RPB + 2 * WIN)   // 80
#define HS_STRIDE 17
#define NC (RPB + 18)           // 82 segc rows: [i0-9, i0+73)
#define NW (RPB + 2)            // 66 segw rows: [i0-1, i0+65)
#define NROWS (NC + NW)         // 148
#define NSLOT (NROWS * 8)       // 1184 lane-slots (8 chunks/row)
#define NBLK 2048

// edge test straight from global seg (fallback only; zero-pad semantics)
__device__ inline int edge_at(const float* __restrict__ seg, int k, int j)
{
    if ((unsigned)k >= (unsigned)HW || (unsigned)j >= (unsigned)HW) return 0;
    if (seg[k * HW + j] == 0.f) return 0;
    bool all9 = true;
    #pragma unroll
    for (int dy = -1; dy <= 1; ++dy)
        #pragma unroll
        for (int dx = -1; dx <= 1; ++dx) {
            const int kk = k + dy, jj = j + dx;
            const float v = ((unsigned)kk < (unsigned)HW && (unsigned)jj < (unsigned)HW)
                            ? seg[kk * HW + jj] : 0.f;
            all9 = all9 && (v != 0.f);
        }
    return all9 ? 0 : 1;
}

// ------------- Fused kernel: windowed row-pass + column EDT + reduce -------
// 1D grid of 2048 blocks, block 256. XCD-aware decode: bid%8 selects the
// row band (it = (bid&7)*2 + bit9), so each XCD's private L2 sees ~1.2MB.
__global__ __launch_bounds__(256)
void k_main(const float* __restrict__ pred, const float* __restrict__ targ,
            float* __restrict__ partial, unsigned* __restrict__ counter,
            float* __restrict__ out)
{
    const int t   = threadIdx.x;
    const int bid = blockIdx.x;               // 0..2047
    const int xcd = bid & 7;
    const int sub = bid >> 3;                 // 0..255
    const int jt  = sub & 63;                 // col tile 0..63
    const int r2  = sub >> 6;                 // 0..3
    const int mc  = r2 & 1;                   // image direction
    const int it  = xcd * 2 + (r2 >> 1);      // row chunk 0..15 (band per XCD)
    const int j0 = jt * 16;
    const int i0 = it * RPB;
    const float* __restrict__ segc = mc ? targ : pred;   // image whose DT we take
    const float* __restrict__ segw = mc ? pred : targ;   // OTHER image (weights)

    __shared__ unsigned s_m[NROWS];          // u32 row masks (segc then segw)
    __shared__ float hs[KROWS * HS_STRIDE];
    __shared__ unsigned short esb[RPB];
    __shared__ float wsum[4];
    __shared__ int s_last;

    // 32-col window: cols [W0, W0+32); tile at bits 8..23.
    // W0 = 16*jt - 8 is a multiple of 4 -> float4 chunks 16B-aligned and
    // never straddle the image border.
    const int W0 = j0 - 8;

    // Phase 1: stage window bits — 8 lanes per row, coalesced float4 loads.
    // All 5 cold loads issued before any shfl-combine (were serialized
    // load->shfl rounds; now one latency exposure instead of five).
    float4 v[5];
    int rowA[5];
    #pragma unroll
    for (int itr = 0; itr < 5; ++itr) {
        const int idx = t + itr * 256;
        v[itr] = make_float4(0.f, 0.f, 0.f, 0.f);
        rowA[itr] = 0;
        if (idx < NSLOT) {
            const int row = idx >> 3;
            rowA[itr] = row;
            const int c4 = idx & 7;
            const int isW = row >= NC;
            const int gr  = isW ? (i0 - 1 + (row - NC)) : (i0 - 9 + row);
            const int c   = W0 + c4 * 4;
            if ((unsigned)gr < (unsigned)HW && (unsigned)c <= 1020u) {
                const float* __restrict__ base = isW ? segw : segc;
                v[itr] = *(const float4*)&base[gr * HW + c];
            }
        }
    }
    #pragma unroll
    for (int itr = 0; itr < 5; ++itr) {
        const int idx = t + itr * 256;
        unsigned partm = 0;
        if (idx < NSLOT) {
            const int c4 = idx & 7;
            const unsigned by = (unsigned)(v[itr].x != 0.f)
                              | ((unsigned)(v[itr].y != 0.f) << 1)
                              | ((unsigned)(v[itr].z != 0.f) << 2)
                              | ((unsigned)(v[itr].w != 0.f) << 3);
            partm = by << (4 * c4);
        }
        partm |= __shfl_xor(partm, 1);
        partm |= __shfl_xor(partm, 2);
        partm |= __shfl_xor(partm, 4);
        if (idx < NSLOT && (t & 7) == 0) s_m[rowA[itr]] = partm;
    }
    __syncthreads();

    // Phase 2a: weight edge words (other image), rows [i0, i0+64)
    if (t < RPB) {
        const unsigned sA = s_m[NC + t], sB = s_m[NC + t + 1], sC = s_m[NC + t + 2];
        const unsigned va = sA & sB & sC;
        const unsigned er = va & (va << 1) & (va >> 1);
        const unsigned edge = sB & ~er;          // tile bits 8..23 have valid nbrs
        esb[t] = (unsigned short)((edge >> 8) & 0xFFFFu);
    }
    // Phase 2b: windowed row-pass -> h = g^2 + kr^2 (threads 0..79, u32 ops)
    if (t < KROWS) {
        const int kr = i0 - WIN + t;             // edge row for hs row t
        float* __restrict__ hrow = &hs[t * HS_STRIDE];
        if ((unsigned)kr < (unsigned)HW) {
            const unsigned sA = s_m[t], sB = s_m[t + 1], sC = s_m[t + 2];
            const unsigned va = sA & sB & sC;
            const unsigned er = va & (va << 1) & (va >> 1);
            // bits 0/31 lack a col-neighbor: excluded as edge candidates; any
            // such miss is >=8 cols from the tile -> covered by the 64 check
            const unsigned edge = (sB & ~er) & 0x7FFFFFFEu;
            const float krk = (float)(kr * kr);
            #pragma unroll
            for (int jc = 0; jc < 16; ++jc) {
                const int p = 8 + jc;            // p in [8,24)
                const unsigned mle = edge & ((1u << (p + 1)) - 1u);
                const unsigned mge = edge >> p;
                int g = 1 << 20;
                if (mle) g = p - (31 - __clz(mle));
                if (mge) g = min(g, __ffs(mge) - 1);
                hrow[jc] = (g < (1 << 20)) ? fmaf((float)g, (float)g, krk) : 1e30f;
            }
        } else {
            #pragma unroll
            for (int jc = 0; jc < 16; ++jc) hrow[jc] = 1e30f;
        }
    }
    __syncthreads();

    // Phase 3: column EDT (windowed, exact) + weighted sum
    const int jj = t & 15;
    const int iw = t >> 4;                       // 0..15, each owns 4 rows
    float lsum = 0.f;
    {
        const int ib = i0 + iw * 4;              // 4 consecutive output rows
        const int kkS = iw * 4;                  // = (ib-WIN) - (i0-WIN)
        float b0 = 3e38f, b1 = 3e38f, b2 = 3e38f, b3 = 3e38f;
        float kf = (float)(ib - WIN);
        const float m0 = -2.f * (float)(ib);
        const float m1 = -2.f * (float)(ib + 1);
        const float m2 = -2.f * (float)(ib + 2);
        const float m3 = -2.f * (float)(ib + 3);
        #pragma unroll
        for (int kk = kkS; kk < kkS + 2 * WIN + 4; ++kk) {
            const float hvv = hs[kk * HS_STRIDE + jj];
            b0 = fminf(b0, fmaf(m0, kf, hvv));
            b1 = fminf(b1, fmaf(m1, kf, hvv));
            b2 = fminf(b2, fmaf(m2, kf, hvv));
            b3 = fminf(b3, fmaf(m3, kf, hvv));
            kf += 1.f;
        }
        const int sLo = max(0, ib - WIN);
        const int sHi = min(HW - 1, ib + WIN + 3);
        float bs[4] = {b0, b1, b2, b3};
        #pragma unroll
        for (int w = 0; w < 4; ++w) {
            const int i = ib + w;
            float D2 = (float)(i * i) + bs[w];
            // exact iff no missed candidate can beat D2:
            //   col-window misses: dist^2 >= 8^2 = 64
            //   row-window misses: dist^2 >= dl^2 / dr^2
            const int dl = i - sLo + 1, dr = sHi + 1 - i;
            const bool need = (D2 > 64.f) ||
                              ((sLo > 0) && (D2 > (float)(dl * dl))) ||
                              ((sHi < HW - 1) && (D2 > (float)(dr * dr)));
            if (need) {  // statistically-dead exact fallback (global scan)
                const int jg = j0 + jj;
                float bb = 1e6f - (float)jg;     // empty-row/empty-image floor
                bb = bb * bb;
                for (int k = 0; k < HW; ++k) {
                    const float rowt = (float)((i - k) * (i - k));
                    if (rowt >= bb) continue;
                    for (int d = 0; d < HW; ++d) {
                        const float dd = rowt + (float)(d * d);
                        if (dd >= bb) break;
                        if (edge_at(segc, k, jg - d) || edge_at(segc, k, jg + d)) {
                            bb = dd; break;
                        }
                    }
                }
                D2 = bb;
            }
            const unsigned wbit = (esb[i - i0] >> jj) & 1u;
            lsum += wbit ? sqrtf(D2) : 0.f;
        }
    }

    // reduce: wave shuffle then cross-wave via LDS
    #pragma unroll
    for (int off = 32; off > 0; off >>= 1) lsum += __shfl_down(lsum, off);
    if ((t & 63) == 0) wsum[t >> 6] = lsum;
    __syncthreads();

    // Fused finalization: last block to arrive reduces all partials.
    if (t == 0) {
        const float ps = wsum[0] + wsum[1] + wsum[2] + wsum[3];
        // agent-scope store: must reach the coherence point (cross-XCD reader)
        __hip_atomic_store(&partial[bid], ps, __ATOMIC_RELAXED,
                           __HIP_MEMORY_SCOPE_AGENT);
        const unsigned old = __hip_atomic_fetch_add(counter, 1u, __ATOMIC_ACQ_REL,
                                                    __HIP_MEMORY_SCOPE_AGENT);
        s_last = (old == (unsigned)(NBLK - 1));
    }
    __syncthreads();
    if (s_last) {
        float s = 0.f;
        #pragma unroll
        for (int q = 0; q < 8; ++q)
            s += __hip_atomic_load(&partial[t + q * 256], __ATOMIC_RELAXED,
                                   __HIP_MEMORY_SCOPE_AGENT);
        #pragma unroll
        for (int off = 32; off > 0; off >>= 1) s += __shfl_down(s, off);
        if ((t & 63) == 0) wsum[t >> 6] = s;
        __syncthreads();
        if (t == 0) {
            const float tot = wsum[0] + wsum[1] + wsum[2] + wsum[3];
            const float loss = tot * (1.f / (2.f * 1024.f * 1024.f));
            out[0] = 1.f / (1.f + expf(-loss));
        }
    }
}

extern "C" void kernel_launch(void* const* d_in, const int* in_sizes, int n_in,
                              void* d_out, int out_size, void* d_ws, size_t ws_size,
                              hipStream_t stream)
{
    const float* preds   = (const float*)d_in[0];
    const float* targets = (const float*)d_in[1];
    float* out = (float*)d_out;

    float* partial    = (float*)d_ws;                        // 8 KB
    unsigned* counter = (unsigned*)((char*)d_ws + 8192);     // 4 B

    hipMemsetAsync(counter, 0, sizeof(unsigned), stream);    // re-zero after poison
    k_main<<<dim3(NBLK), 256, 0, stream>>>(preds, targets, partial, counter, out);
}

// Round 2
// 89.663 us; speedup vs baseline: 1.1643x; 1.1643x over previous
//
#include <hip/hip_runtime.h>
#include <math.h>

// BoundaryDistanceLoss — H=W=1024 binary masks (float 0/1).
// edges = seg - erode3x3(seg); exact EDT of edges; loss =
// sigmoid((mean(target_edges*pred_dt) + mean(pred_edges*target_dt))/2).
//
// R16->R17: fused finalization kept, but the ACQ_REL agent atomic is replaced
// by RELAXED + explicit s_waitcnt vmcnt(0). R16 post-mortem: acq_rel at agent
// scope lowers to buffer_wbl2 sc1 (full L2 writeback) + buffer_inv sc0 sc1
// (L1+L2 invalidate) PER BLOCK -> 2048 serialized L2 walks, every block's
// cached inputs invalidated; k_main 20->53us, VALUBusy 15%, HBM 1%. The
// partial[] store is itself an agent-scope atomic (performs at the coherence
// point), so ordering needs NO cache maintenance: relaxed store -> vmcnt(0)
// (store arrived at coherence point) -> relaxed fetch_add. Reader (the single
// last block) observes counter==2047 only after all 2048 RMWs, each issued
// after its partial landed; relaxed agent atomic loads read the coherence
// point directly. Math identical to R13-R16 (absmax 0.0).
//
// ws layout: partial (8KB f32) + counter (4B u32 at offset 8192).

#define HW 1024
#define WIN 8
#define RPB 64
#define KROWS (RPB + 2 * WIN)   // 80
#define HS_STRIDE 17
#define NC (RPB + 18)           // 82 segc rows: [i0-9, i0+73)
#define NW (RPB + 2)            // 66 segw rows: [i0-1, i0+65)
#define NROWS (NC + NW)         // 148
#define NSLOT (NROWS * 8)       // 1184 lane-slots (8 chunks/row)
#define NBLK 2048

// edge test straight from global seg (fallback only; zero-pad semantics)
__device__ inline int edge_at(const float* __restrict__ seg, int k, int j)
{
    if ((unsigned)k >= (unsigned)HW || (unsigned)j >= (unsigned)HW) return 0;
    if (seg[k * HW + j] == 0.f) return 0;
    bool all9 = true;
    #pragma unroll
    for (int dy = -1; dy <= 1; ++dy)
        #pragma unroll
        for (int dx = -1; dx <= 1; ++dx) {
            const int kk = k + dy, jj = j + dx;
            const float v = ((unsigned)kk < (unsigned)HW && (unsigned)jj < (unsigned)HW)
                            ? seg[kk * HW + jj] : 0.f;
            all9 = all9 && (v != 0.f);
        }
    return all9 ? 0 : 1;
}

// ------------- Fused kernel: windowed row-pass + column EDT + reduce -------
// 1D grid of 2048 blocks, block 256. XCD-aware decode: bid%8 selects the
// row band (it = (bid&7)*2 + bit9), so each XCD's private L2 sees ~1.2MB.
__global__ __launch_bounds__(256)
void k_main(const float* __restrict__ pred, const float* __restrict__ targ,
            float* __restrict__ partial, unsigned* __restrict__ counter,
            float* __restrict__ out)
{
    const int t   = threadIdx.x;
    const int bid = blockIdx.x;               // 0..2047
    const int xcd = bid & 7;
    const int sub = bid >> 3;                 // 0..255
    const int jt  = sub & 63;                 // col tile 0..63
    const int r2  = sub >> 6;                 // 0..3
    const int mc  = r2 & 1;                   // image direction
    const int it  = xcd * 2 + (r2 >> 1);      // row chunk 0..15 (band per XCD)
    const int j0 = jt * 16;
    const int i0 = it * RPB;
    const float* __restrict__ segc = mc ? targ : pred;   // image whose DT we take
    const float* __restrict__ segw = mc ? pred : targ;   // OTHER image (weights)

    __shared__ unsigned s_m[NROWS];          // u32 row masks (segc then segw)
    __shared__ float hs[KROWS * HS_STRIDE];
    __shared__ unsigned short esb[RPB];
    __shared__ float wsum[4];
    __shared__ int s_last;

    // 32-col window: cols [W0, W0+32); tile at bits 8..23.
    // W0 = 16*jt - 8 is a multiple of 4 -> float4 chunks 16B-aligned and
    // never straddle the image border.
    const int W0 = j0 - 8;

    // Phase 1: stage window bits — 8 lanes per row, coalesced float4 loads.
    // All 5 cold loads issued before any shfl-combine (one latency exposure
    // instead of five serialized load->shfl rounds).
    float4 v[5];
    int rowA[5];
    #pragma unroll
    for (int itr = 0; itr < 5; ++itr) {
        const int idx = t + itr * 256;
        v[itr] = make_float4(0.f, 0.f, 0.f, 0.f);
        rowA[itr] = 0;
        if (idx < NSLOT) {
            const int row = idx >> 3;
            rowA[itr] = row;
            const int c4 = idx & 7;
            const int isW = row >= NC;
            const int gr  = isW ? (i0 - 1 + (row - NC)) : (i0 - 9 + row);
            const int c   = W0 + c4 * 4;
            if ((unsigned)gr < (unsigned)HW && (unsigned)c <= 1020u) {
                const float* __restrict__ base = isW ? segw : segc;
                v[itr] = *(const float4*)&base[gr * HW + c];
            }
        }
    }
    #pragma unroll
    for (int itr = 0; itr < 5; ++itr) {
        const int idx = t + itr * 256;
        unsigned partm = 0;
        if (idx < NSLOT) {
            const int c4 = idx & 7;
            const unsigned by = (unsigned)(v[itr].x != 0.f)
                              | ((unsigned)(v[itr].y != 0.f) << 1)
                              | ((unsigned)(v[itr].z != 0.f) << 2)
                              | ((unsigned)(v[itr].w != 0.f) << 3);
            partm = by << (4 * c4);
        }
        partm |= __shfl_xor(partm, 1);
        partm |= __shfl_xor(partm, 2);
        partm |= __shfl_xor(partm, 4);
        if (idx < NSLOT && (t & 7) == 0) s_m[rowA[itr]] = partm;
    }
    __syncthreads();

    // Phase 2a: weight edge words (other image), rows [i0, i0+64)
    if (t < RPB) {
        const unsigned sA = s_m[NC + t], sB = s_m[NC + t + 1], sC = s_m[NC + t + 2];
        const unsigned va = sA & sB & sC;
        const unsigned er = va & (va << 1) & (va >> 1);
        const unsigned edge = sB & ~er;          // tile bits 8..23 have valid nbrs
        esb[t] = (unsigned short)((edge >> 8) & 0xFFFFu);
    }
    // Phase 2b: windowed row-pass -> h = g^2 + kr^2 (threads 0..79, u32 ops)
    if (t < KROWS) {
        const int kr = i0 - WIN + t;             // edge row for hs row t
        float* __restrict__ hrow = &hs[t * HS_STRIDE];
        if ((unsigned)kr < (unsigned)HW) {
            const unsigned sA = s_m[t], sB = s_m[t + 1], sC = s_m[t + 2];
            const unsigned va = sA & sB & sC;
            const unsigned er = va & (va << 1) & (va >> 1);
            // bits 0/31 lack a col-neighbor: excluded as edge candidates; any
            // such miss is >=8 cols from the tile -> covered by the 64 check
            const unsigned edge = (sB & ~er) & 0x7FFFFFFEu;
            const float krk = (float)(kr * kr);
            #pragma unroll
            for (int jc = 0; jc < 16; ++jc) {
                const int p = 8 + jc;            // p in [8,24)
                const unsigned mle = edge & ((1u << (p + 1)) - 1u);
                const unsigned mge = edge >> p;
                int g = 1 << 20;
                if (mle) g = p - (31 - __clz(mle));
                if (mge) g = min(g, __ffs(mge) - 1);
                hrow[jc] = (g < (1 << 20)) ? fmaf((float)g, (float)g, krk) : 1e30f;
            }
        } else {
            #pragma unroll
            for (int jc = 0; jc < 16; ++jc) hrow[jc] = 1e30f;
        }
    }
    __syncthreads();

    // Phase 3: column EDT (windowed, exact) + weighted sum
    const int jj = t & 15;
    const int iw = t >> 4;                       // 0..15, each owns 4 rows
    float lsum = 0.f;
    {
        const int ib = i0 + iw * 4;              // 4 consecutive output rows
        const int kkS = iw * 4;                  // = (ib-WIN) - (i0-WIN)
        float b0 = 3e38f, b1 = 3e38f, b2 = 3e38f, b3 = 3e38f;
        float kf = (float)(ib - WIN);
        const float m0 = -2.f * (float)(ib);
        const float m1 = -2.f * (float)(ib + 1);
        const float m2 = -2.f * (float)(ib + 2);
        const float m3 = -2.f * (float)(ib + 3);
        #pragma unroll
        for (int kk = kkS; kk < kkS + 2 * WIN + 4; ++kk) {
            const float hvv = hs[kk * HS_STRIDE + jj];
            b0 = fminf(b0, fmaf(m0, kf, hvv));
            b1 = fminf(b1, fmaf(m1, kf, hvv));
            b2 = fminf(b2, fmaf(m2, kf, hvv));
            b3 = fminf(b3, fmaf(m3, kf, hvv));
            kf += 1.f;
        }
        const int sLo = max(0, ib - WIN);
        const int sHi = min(HW - 1, ib + WIN + 3);
        float bs[4] = {b0, b1, b2, b3};
        #pragma unroll
        for (int w = 0; w < 4; ++w) {
            const int i = ib + w;
            float D2 = (float)(i * i) + bs[w];
            // exact iff no missed candidate can beat D2:
            //   col-window misses: dist^2 >= 8^2 = 64
            //   row-window misses: dist^2 >= dl^2 / dr^2
            const int dl = i - sLo + 1, dr = sHi + 1 - i;
            const bool need = (D2 > 64.f) ||
                              ((sLo > 0) && (D2 > (float)(dl * dl))) ||
                              ((sHi < HW - 1) && (D2 > (float)(dr * dr)));
            if (need) {  // statistically-dead exact fallback (global scan)
                const int jg = j0 + jj;
                float bb = 1e6f - (float)jg;     // empty-row/empty-image floor
                bb = bb * bb;
                for (int k = 0; k < HW; ++k) {
                    const float rowt = (float)((i - k) * (i - k));
                    if (rowt >= bb) continue;
                    for (int d = 0; d < HW; ++d) {
                        const float dd = rowt + (float)(d * d);
                        if (dd >= bb) break;
                        if (edge_at(segc, k, jg - d) || edge_at(segc, k, jg + d)) {
                            bb = dd; break;
                        }
                    }
                }
                D2 = bb;
            }
            const unsigned wbit = (esb[i - i0] >> jj) & 1u;
            lsum += wbit ? sqrtf(D2) : 0.f;
        }
    }

    // reduce: wave shuffle then cross-wave via LDS
    #pragma unroll
    for (int off = 32; off > 0; off >>= 1) lsum += __shfl_down(lsum, off);
    if ((t & 63) == 0) wsum[t >> 6] = lsum;
    __syncthreads();

    // Fused finalization: last block to arrive reduces all partials.
    // RELAXED atomics only — no release/acquire fences (no buffer_wbl2 /
    // buffer_inv). Ordering via vmcnt(0): the agent-scope atomic store has
    // performed at the coherence point when it retires from vmcnt.
    if (t == 0) {
        const float ps = wsum[0] + wsum[1] + wsum[2] + wsum[3];
        __hip_atomic_store(&partial[bid], ps, __ATOMIC_RELAXED,
                           __HIP_MEMORY_SCOPE_AGENT);
        asm volatile("s_waitcnt vmcnt(0)" ::: "memory");
        const unsigned old = __hip_atomic_fetch_add(counter, 1u, __ATOMIC_RELAXED,
                                                    __HIP_MEMORY_SCOPE_AGENT);
        s_last = (old == (unsigned)(NBLK - 1));
    }
    __syncthreads();
    if (s_last) {
        float s = 0.f;
        #pragma unroll
        for (int q = 0; q < 8; ++q)
            s += __hip_atomic_load(&partial[t + q * 256], __ATOMIC_RELAXED,
                                   __HIP_MEMORY_SCOPE_AGENT);
        #pragma unroll
        for (int off = 32; off > 0; off >>= 1) s += __shfl_down(s, off);
        if ((t & 63) == 0) wsum[t >> 6] = s;
        __syncthreads();
        if (t == 0) {
            const float tot = wsum[0] + wsum[1] + wsum[2] + wsum[3];
            const float loss = tot * (1.f / (2.f * 1024.f * 1024.f));
            out[0] = 1.f / (1.f + expf(-loss));
        }
    }
}

extern "C" void kernel_launch(void* const* d_in, const int* in_sizes, int n_in,
                              void* d_out, int out_size, void* d_ws, size_t ws_size,
                              hipStream_t stream)
{
    const float* preds   = (const float*)d_in[0];
    const float* targets = (const float*)d_in[1];
    float* out = (float*)d_out;

    float* partial    = (float*)d_ws;                        // 8 KB
    unsigned* counter = (unsigned*)((char*)d_ws + 8192);     // 4 B

    hipMemsetAsync(counter, 0, sizeof(unsigned), stream);    // re-zero after poison
    k_main<<<dim3(NBLK), 256, 0, stream>>>(preds, targets, partial, counter, out);
}

// Round 3
// 69.403 us; speedup vs baseline: 1.5043x; 1.2919x over previous
//
#include <hip/hip_runtime.h>
#include <math.h>

// BoundaryDistanceLoss — H=W=1024 binary masks (float 0/1).
// edges = seg - erode3x3(seg); exact EDT of edges; loss =
// sigmoid((mean(target_edges*pred_dt) + mean(pred_edges*target_dt))/2).
//
// R17->R18: REVERT fused finalization (falsified: 2048 same-address
// agent-scope RMWs serialize at the coherence point ~17us inside k_main;
// two-kernel k_fin+gap costs only ~5us). Back to R15's k_main + k_fin.
// Kept from R16/R17: phase-1's 5 cold float4 loads hoisted before the
// shfl-combine pass (poison fill evicts L2+L3 every iter -> loads are
// HBM-cold ~900cy; one latency exposure instead of five).
// New: phase-2b redistributed across all 256 threads (was 80 threads x 16
// clz/ffs entries = 1.25 waves working, 2.75 idle at the barrier; now 256
// threads x 5 entries, per-row mask recomputed from broadcast LDS reads).
// Math identical to R13-R17 (absmax 0.0).
//
// ws layout: partial (8KB f32) only.

#define HW 1024
#define WIN 8
#define RPB 64
#define KROWS (RPB + 2 * WIN)   // 80
#define HS_STRIDE 17
#define NC (RPB + 18)           // 82 segc rows: [i0-9, i0+73)
#define NW (RPB + 2)            // 66 segw rows: [i0-1, i0+65)
#define NROWS (NC + NW)         // 148
#define NSLOT (NROWS * 8)       // 1184 lane-slots (8 chunks/row)
#define NENT (KROWS * 16)       // 1280 phase-2b entries (row, jc)
#define NBLK 2048

// edge test straight from global seg (fallback only; zero-pad semantics)
__device__ inline int edge_at(const float* __restrict__ seg, int k, int j)
{
    if ((unsigned)k >= (unsigned)HW || (unsigned)j >= (unsigned)HW) return 0;
    if (seg[k * HW + j] == 0.f) return 0;
    bool all9 = true;
    #pragma unroll
    for (int dy = -1; dy <= 1; ++dy)
        #pragma unroll
        for (int dx = -1; dx <= 1; ++dx) {
            const int kk = k + dy, jj = j + dx;
            const float v = ((unsigned)kk < (unsigned)HW && (unsigned)jj < (unsigned)HW)
                            ? seg[kk * HW + jj] : 0.f;
            all9 = all9 && (v != 0.f);
        }
    return all9 ? 0 : 1;
}

// ------------- Fused kernel: windowed row-pass + column EDT + partial -------
// 1D grid of 2048 blocks, block 256. XCD-aware decode: bid%8 selects the
// row band (it = (bid&7)*2 + bit9), so each XCD's private L2 sees ~1.2MB.
__global__ __launch_bounds__(256)
void k_main(const float* __restrict__ pred, const float* __restrict__ targ,
            float* __restrict__ partial)
{
    const int t   = threadIdx.x;
    const int bid = blockIdx.x;               // 0..2047
    const int xcd = bid & 7;
    const int sub = bid >> 3;                 // 0..255
    const int jt  = sub & 63;                 // col tile 0..63
    const int r2  = sub >> 6;                 // 0..3
    const int mc  = r2 & 1;                   // image direction
    const int it  = xcd * 2 + (r2 >> 1);      // row chunk 0..15 (band per XCD)
    const int j0 = jt * 16;
    const int i0 = it * RPB;
    const float* __restrict__ segc = mc ? targ : pred;   // image whose DT we take
    const float* __restrict__ segw = mc ? pred : targ;   // OTHER image (weights)

    __shared__ unsigned s_m[NROWS];          // u32 row masks (segc then segw)
    __shared__ float hs[KROWS * HS_STRIDE];
    __shared__ unsigned short esb[RPB];
    __shared__ float wsum[4];

    // 32-col window: cols [W0, W0+32); tile at bits 8..23.
    // W0 = 16*jt - 8 is a multiple of 4 -> float4 chunks 16B-aligned and
    // never straddle the image border.
    const int W0 = j0 - 8;

    // Phase 1: stage window bits — 8 lanes per row, coalesced float4 loads.
    // All 5 cold loads issued before any shfl-combine (one HBM-latency
    // exposure instead of five serialized load->shfl rounds).
    float4 v[5];
    int rowA[5];
    #pragma unroll
    for (int itr = 0; itr < 5; ++itr) {
        const int idx = t + itr * 256;
        v[itr] = make_float4(0.f, 0.f, 0.f, 0.f);
        rowA[itr] = 0;
        if (idx < NSLOT) {
            const int row = idx >> 3;
            rowA[itr] = row;
            const int c4 = idx & 7;
            const int isW = row >= NC;
            const int gr  = isW ? (i0 - 1 + (row - NC)) : (i0 - 9 + row);
            const int c   = W0 + c4 * 4;
            if ((unsigned)gr < (unsigned)HW && (unsigned)c <= 1020u) {
                const float* __restrict__ base = isW ? segw : segc;
                v[itr] = *(const float4*)&base[gr * HW + c];
            }
        }
    }
    #pragma unroll
    for (int itr = 0; itr < 5; ++itr) {
        const int idx = t + itr * 256;
        unsigned partm = 0;
        if (idx < NSLOT) {
            const int c4 = idx & 7;
            const unsigned by = (unsigned)(v[itr].x != 0.f)
                              | ((unsigned)(v[itr].y != 0.f) << 1)
                              | ((unsigned)(v[itr].z != 0.f) << 2)
                              | ((unsigned)(v[itr].w != 0.f) << 3);
            partm = by << (4 * c4);
        }
        partm |= __shfl_xor(partm, 1);
        partm |= __shfl_xor(partm, 2);
        partm |= __shfl_xor(partm, 4);
        if (idx < NSLOT && (t & 7) == 0) s_m[rowA[itr]] = partm;
    }
    __syncthreads();

    // Phase 2a: weight edge words (other image), rows [i0, i0+64)
    if (t < RPB) {
        const unsigned sA = s_m[NC + t], sB = s_m[NC + t + 1], sC = s_m[NC + t + 2];
        const unsigned va = sA & sB & sC;
        const unsigned er = va & (va << 1) & (va >> 1);
        const unsigned edge = sB & ~er;          // tile bits 8..23 have valid nbrs
        esb[t] = (unsigned short)((edge >> 8) & 0xFFFFu);
    }
    // Phase 2b: windowed row-pass -> h = g^2 + kr^2. Redistributed: 1280
    // (row, jc) entries over all 256 threads (5 each). Mask recompute per
    // entry is 3 broadcast LDS reads + ~6 ALU — cheaper than idling 2.75
    // waves behind an 80-thread x16-iteration serial loop.
    #pragma unroll
    for (int itr = 0; itr < 5; ++itr) {
        const int e   = t + itr * 256;           // 0..1279, all valid
        const int row = e >> 4;                  // 0..79
        const int jc  = e & 15;
        const int kr  = i0 - WIN + row;          // edge row for hs row
        float hv = 1e30f;
        if ((unsigned)kr < (unsigned)HW) {
            const unsigned sA = s_m[row], sB = s_m[row + 1], sC = s_m[row + 2];
            const unsigned va = sA & sB & sC;
            const unsigned er = va & (va << 1) & (va >> 1);
            // bits 0/31 lack a col-neighbor: excluded as edge candidates; any
            // such miss is >=8 cols from the tile -> covered by the 64 check
            const unsigned edge = (sB & ~er) & 0x7FFFFFFEu;
            const int p = 8 + jc;                // p in [8,24)
            const unsigned mle = edge & ((1u << (p + 1)) - 1u);
            const unsigned mge = edge >> p;
            int g = 1 << 20;
            if (mle) g = p - (31 - __clz(mle));
            if (mge) g = min(g, __ffs(mge) - 1);
            if (g < (1 << 20))
                hv = fmaf((float)g, (float)g, (float)(kr * kr));
        }
        hs[row * HS_STRIDE + jc] = hv;
    }
    __syncthreads();

    // Phase 3: column EDT (windowed, exact) + weighted sum
    const int jj = t & 15;
    const int iw = t >> 4;                       // 0..15, each owns 4 rows
    float lsum = 0.f;
    {
        const int ib = i0 + iw * 4;              // 4 consecutive output rows
        const int kkS = iw * 4;                  // = (ib-WIN) - (i0-WIN)
        float b0 = 3e38f, b1 = 3e38f, b2 = 3e38f, b3 = 3e38f;
        float kf = (float)(ib - WIN);
        const float m0 = -2.f * (float)(ib);
        const float m1 = -2.f * (float)(ib + 1);
        const float m2 = -2.f * (float)(ib + 2);
        const float m3 = -2.f * (float)(ib + 3);
        #pragma unroll
        for (int kk = kkS; kk < kkS + 2 * WIN + 4; ++kk) {
            const float hvv = hs[kk * HS_STRIDE + jj];
            b0 = fminf(b0, fmaf(m0, kf, hvv));
            b1 = fminf(b1, fmaf(m1, kf, hvv));
            b2 = fminf(b2, fmaf(m2, kf, hvv));
            b3 = fminf(b3, fmaf(m3, kf, hvv));
            kf += 1.f;
        }
        const int sLo = max(0, ib - WIN);
        const int sHi = min(HW - 1, ib + WIN + 3);
        float bs[4] = {b0, b1, b2, b3};
        #pragma unroll
        for (int w = 0; w < 4; ++w) {
            const int i = ib + w;
            float D2 = (float)(i * i) + bs[w];
            // exact iff no missed candidate can beat D2:
            //   col-window misses: dist^2 >= 8^2 = 64
            //   row-window misses: dist^2 >= dl^2 / dr^2
            const int dl = i - sLo + 1, dr = sHi + 1 - i;
            const bool need = (D2 > 64.f) ||
                              ((sLo > 0) && (D2 > (float)(dl * dl))) ||
                              ((sHi < HW - 1) && (D2 > (float)(dr * dr)));
            if (need) {  // statistically-dead exact fallback (global scan)
                const int jg = j0 + jj;
                float bb = 1e6f - (float)jg;     // empty-row/empty-image floor
                bb = bb * bb;
                for (int k = 0; k < HW; ++k) {
                    const float rowt = (float)((i - k) * (i - k));
                    if (rowt >= bb) continue;
                    for (int d = 0; d < HW; ++d) {
                        const float dd = rowt + (float)(d * d);
                        if (dd >= bb) break;
                        if (edge_at(segc, k, jg - d) || edge_at(segc, k, jg + d)) {
                            bb = dd; break;
                        }
                    }
                }
                D2 = bb;
            }
            const unsigned wbit = (esb[i - i0] >> jj) & 1u;
            lsum += wbit ? sqrtf(D2) : 0.f;
        }
    }

    // reduce: wave shuffle then cross-wave via LDS; ONE plain store per block
    #pragma unroll
    for (int off = 32; off > 0; off >>= 1) lsum += __shfl_down(lsum, off);
    if ((t & 63) == 0) wsum[t >> 6] = lsum;
    __syncthreads();
    if (t == 0)
        partial[bid] = wsum[0] + wsum[1] + wsum[2] + wsum[3];
}

// ---------------- Kernel C: reduce 2048 partials + sigmoid ----------------
__global__ __launch_bounds__(256)
void k_fin(const float* __restrict__ partial, float* __restrict__ out)
{
    const int t = threadIdx.x;
    float s = 0.f;
    #pragma unroll
    for (int q = 0; q < 8; ++q) s += partial[t + q * 256];
    #pragma unroll
    for (int off = 32; off > 0; off >>= 1) s += __shfl_down(s, off);
    __shared__ float w[4];
    if ((t & 63) == 0) w[t >> 6] = s;
    __syncthreads();
    if (t == 0) {
        const float tot = w[0] + w[1] + w[2] + w[3];
        const float loss = tot * (1.f / (2.f * 1024.f * 1024.f));
        out[0] = 1.f / (1.f + expf(-loss));
    }
}

extern "C" void kernel_launch(void* const* d_in, const int* in_sizes, int n_in,
                              void* d_out, int out_size, void* d_ws, size_t ws_size,
                              hipStream_t stream)
{
    const float* preds   = (const float*)d_in[0];
    const float* targets = (const float*)d_in[1];
    float* out = (float*)d_out;

    float* partial = (float*)d_ws;   // 8 KB

    k_main<<<dim3(NBLK), 256, 0, stream>>>(preds, targets, partial);
    k_fin<<<1, 256, 0, stream>>>(partial, out);
}